// Round 1
// baseline (416.311 us; speedup 1.0000x reference)
//
#include <hip/hip_runtime.h>

#define O_DIM 256
#define C_DIM 256
#define P_DIM 96
#define KHW 51
#define NSP 2601      // 51*51
#define NT 64         // spatial tile (in m = kw*51 + kh ordering)
#define NTILES 41     // ceil(2601/64)
#define GROUPS 4      // blocks per o
#define LDSV 104      // LDS row stride (bf16 elems): 16B-aligned rows, conflict-friendly

typedef __attribute__((ext_vector_type(8))) short short8v;
typedef __attribute__((ext_vector_type(4))) float float4v;

__device__ __forceinline__ unsigned f2bf(float f) {
  union { float f; unsigned u; } v; v.f = f;
  return (v.u + 0x7FFFu + ((v.u >> 16) & 1u)) >> 16;  // RNE f32->bf16
}

__global__ __launch_bounds__(256) void smp_fused(
    const float* __restrict__ xg,   // (1,2,51,51)
    const float* __restrict__ wc,   // (O,P,2)
    const float* __restrict__ rad,  // (O,P,1,1)
    const float* __restrict__ wts,  // (O,C,P)
    float* __restrict__ out)        // (O,C,51,51) f32
{
  __shared__ unsigned short Vt[2][NT * LDSV];  // B^T tiles, double-buffered

  const int b = blockIdx.x;
  const int o = b >> 2;
  const int grp = b & 3;
  const int tid = threadIdx.x;
  const int wave = tid >> 6;
  const int lane = tid & 63;
  const int row16 = lane & 15;
  const int kgrp = lane >> 4;

  // ---- A fragments (weights for this o), bf16, kept in registers all kernel.
  // A[row=c][k=p]: lane holds row = (lane&15), k = kgrp*8 + j (j=0..7), per 16x16x32.
  short8v afr[4][3];  // [mfrag][kstep]
  {
    const float* Wo = wts + (size_t)o * (C_DIM * P_DIM);
#pragma unroll
    for (int mf = 0; mf < 4; ++mf) {
      const float* src = Wo + (wave * 64 + mf * 16 + row16) * P_DIM;
#pragma unroll
      for (int ks = 0; ks < 3; ++ks) {
        const float4 a = *(const float4*)(src + ks * 32 + kgrp * 8);
        const float4 c = *(const float4*)(src + ks * 32 + kgrp * 8 + 4);
        short8v f;
        f[0] = (short)f2bf(a.x); f[1] = (short)f2bf(a.y);
        f[2] = (short)f2bf(a.z); f[3] = (short)f2bf(a.w);
        f[4] = (short)f2bf(c.x); f[5] = (short)f2bf(c.y);
        f[6] = (short)f2bf(c.z); f[7] = (short)f2bf(c.w);
        afr[mf][ks] = f;
      }
    }
  }

  // vals phase mapping: 4 threads per m, each handles 24 of the 96 points
  const int mloc = tid >> 2;  // 0..63
  const int sp = tid & 3;     // 24-point chunk
  const float* wcp = wc + ((size_t)o * P_DIM + sp * 24) * 2;
  const float* rp  = rad + (size_t)o * P_DIM + sp * 24;

  int bufi = 0;
  for (int tile = grp; tile < NTILES; tile += GROUPS, bufi ^= 1) {
    const int m0 = tile * NT;

    // ---- vals: triangular basis + count-normalize, exact IEEE chain for the count
    {
      int mg = m0 + mloc;
      int mc = mg < NSP ? mg : NSP - 1;
      int kw = mc / KHW;
      int kh = mc - kw * KHW;
      float gy = xg[kh * KHW + kw];         // x[0,0,kh,kw]
      float gx = xg[NSP + kh * KHW + kw];   // x[0,1,kh,kw]
      float t[24];
      int cnt = 0;
#pragma unroll
      for (int i = 0; i < 24; ++i) {
        // EXACT numpy-matching sequence: sub,abs,sub,abs,add, true-div, sub
        float d = fabsf(wcp[2 * i] - gy) + fabsf(wcp[2 * i + 1] - gx);
        float v = 1.0f - d / rp[i];
        v = v > 0.0f ? v : 0.0f;
        t[i] = v;
        cnt += (v != 0.0f);
      }
      cnt += __shfl_xor(cnt, 1);
      cnt += __shfl_xor(cnt, 2);
      const float inv = 1.0f / ((float)cnt + 1e-6f);  // feeds bf16; 2-rounding ok
      unsigned* dst = (unsigned*)(&Vt[bufi][mloc * LDSV + sp * 24]);
#pragma unroll
      for (int i = 0; i < 12; ++i) {
        dst[i] = f2bf(t[2 * i] * inv) | (f2bf(t[2 * i + 1] * inv) << 16);
      }
    }
    __syncthreads();

    // ---- GEMM: (256 x 96) @ (96 x 64) per tile; wave owns 64 c-rows
    float4v acc[4][4];
#pragma unroll
    for (int mf = 0; mf < 4; ++mf)
#pragma unroll
      for (int nf = 0; nf < 4; ++nf)
        acc[mf][nf] = (float4v){0.f, 0.f, 0.f, 0.f};

#pragma unroll
    for (int ks = 0; ks < 3; ++ks) {
      short8v bfr[4];
#pragma unroll
      for (int nf = 0; nf < 4; ++nf) {
        // B[k][col]: lane reads 8 consecutive k at its col => Vt[m][k..k+7]
        bfr[nf] = *(const short8v*)(&Vt[bufi][(nf * 16 + row16) * LDSV + ks * 32 + kgrp * 8]);
      }
#pragma unroll
      for (int mf = 0; mf < 4; ++mf)
#pragma unroll
        for (int nf = 0; nf < 4; ++nf)
          acc[mf][nf] = __builtin_amdgcn_mfma_f32_16x16x32_bf16(
              afr[mf][ks], bfr[nf], acc[mf][nf], 0, 0, 0);
    }

    // ---- permuted store: out[o][c][50-kw][kh]; C/D: col=lane&15 (m), row=kgrp*4+reg (c)
    const int rowb = kgrp * 4;
#pragma unroll
    for (int nf = 0; nf < 4; ++nf) {
      int m = m0 + nf * 16 + row16;
      if (m < NSP) {
        int kw = m / KHW;
        int kh = m - kw * KHW;
        float* ob = out + (size_t)o * (C_DIM * NSP) + (KHW - 1 - kw) * KHW + kh;
#pragma unroll
        for (int mf = 0; mf < 4; ++mf) {
          int c0 = wave * 64 + mf * 16 + rowb;
#pragma unroll
          for (int r = 0; r < 4; ++r) {
            ob[(size_t)(c0 + r) * NSP] = acc[mf][nf][r];
          }
        }
      }
    }
    // stores overlap next tile's vals compute; double-buffered LDS needs only
    // the one barrier above per tile.
  }
}

extern "C" void kernel_launch(void* const* d_in, const int* in_sizes, int n_in,
                              void* d_out, int out_size, void* d_ws, size_t ws_size,
                              hipStream_t stream) {
  const float* xg  = (const float*)d_in[0];
  const float* wcp = (const float*)d_in[1];
  const float* rad = (const float*)d_in[2];
  const float* wts = (const float*)d_in[3];
  float* out = (float*)d_out;
  hipLaunchKernelGGL(smp_fused, dim3(O_DIM * GROUPS), dim3(256), 0, stream,
                     xg, wcp, rad, wts, out);
}

// Round 2
// 374.251 us; speedup vs baseline: 1.1124x; 1.1124x over previous
//
#include <hip/hip_runtime.h>

#define O_DIM 256
#define C_DIM 256
#define P_DIM 96
#define KHW 51
#define NSP 2601      // 51*51
#define NT 64         // spatial tile (in m = kw*51 + kh ordering)
#define NTILES 41     // ceil(2601/64)
#define GROUPS 8      // contiguous tile-span groups per (o, c-half)
#define CSPLIT 2      // c dimension split across blocks
#define CB 128        // c rows per block (C_DIM / CSPLIT)
#define LDSV 104      // LDS row stride (bf16 elems)

typedef __attribute__((ext_vector_type(8))) short short8v;
typedef __attribute__((ext_vector_type(4))) float float4v;

__device__ __forceinline__ unsigned f2bf(float f) {
  union { float f; unsigned u; } v; v.f = f;
  return (v.u + 0x7FFFu + ((v.u >> 16) & 1u)) >> 16;  // RNE f32->bf16
}

__global__ __launch_bounds__(256) void smp_fused(
    const float* __restrict__ xg,   // (1,2,51,51)
    const float* __restrict__ wc,   // (O,P,2)
    const float* __restrict__ rad,  // (O,P,1,1)
    const float* __restrict__ wts,  // (O,C,P)
    float* __restrict__ out)        // (O,C,51,51) f32
{
  __shared__ unsigned short Vt[2][NT * LDSV];  // B^T tiles, double-buffered

  const int b = blockIdx.x;
  const int o = b >> 4;                 // / (CSPLIT*GROUPS)
  const int chalf = (b >> 3) & 1;
  const int grp = b & 7;
  const int tid = threadIdx.x;
  const int wave = tid >> 6;
  const int lane = tid & 63;
  const int row16 = lane & 15;
  const int kgrp = lane >> 4;

  // ---- A fragments: this block's 128 c-rows, wave owns 32 of them.
  // A[row=c][k=p]: lane holds row=(lane&15), k=kgrp*8+j, per 16x16x32 layout.
  short8v afr[2][3];  // [mfrag][kstep]
  {
    const float* Wo = wts + (size_t)o * (C_DIM * P_DIM);
#pragma unroll
    for (int mf = 0; mf < 2; ++mf) {
      const float* src = Wo + (chalf * CB + wave * 32 + mf * 16 + row16) * P_DIM;
#pragma unroll
      for (int ks = 0; ks < 3; ++ks) {
        const float4 a = *(const float4*)(src + ks * 32 + kgrp * 8);
        const float4 c = *(const float4*)(src + ks * 32 + kgrp * 8 + 4);
        short8v f;
        f[0] = (short)f2bf(a.x); f[1] = (short)f2bf(a.y);
        f[2] = (short)f2bf(a.z); f[3] = (short)f2bf(a.w);
        f[4] = (short)f2bf(c.x); f[5] = (short)f2bf(c.y);
        f[6] = (short)f2bf(c.z); f[7] = (short)f2bf(c.w);
        afr[mf][ks] = f;
      }
    }
  }

  // vals phase mapping: 4 threads per m, each handles 24 of the 96 points
  const int mloc = tid >> 2;  // 0..63
  const int sp = tid & 3;     // 24-point chunk
  const float* wcp = wc + ((size_t)o * P_DIM + sp * 24) * 2;
  const float* rp  = rad + (size_t)o * P_DIM + sp * 24;

  const int t0 = (grp * NTILES) / GROUPS;
  const int t1 = ((grp + 1) * NTILES) / GROUPS;

  int bufi = 0;
  for (int tile = t0; tile < t1; ++tile, bufi ^= 1) {
    const int m0 = tile * NT;

    // ---- vals: triangular basis + count-normalize (exact IEEE chain for count)
    {
      int mg = m0 + mloc;
      int mc = mg < NSP ? mg : NSP - 1;
      int kw = mc / KHW;
      int kh = mc - kw * KHW;
      float gy = xg[kh * KHW + kw];         // x[0,0,kh,kw]
      float gx = xg[NSP + kh * KHW + kw];   // x[0,1,kh,kw]
      float t[24];
      int cnt = 0;
#pragma unroll
      for (int i = 0; i < 24; ++i) {
        float d = fabsf(wcp[2 * i] - gy) + fabsf(wcp[2 * i + 1] - gx);
        float v = 1.0f - d / rp[i];
        v = v > 0.0f ? v : 0.0f;
        t[i] = v;
        cnt += (v != 0.0f);
      }
      cnt += __shfl_xor(cnt, 1);
      cnt += __shfl_xor(cnt, 2);
      const float inv = 1.0f / ((float)cnt + 1e-6f);  // feeds bf16; 2-rounding ok
      unsigned* dst = (unsigned*)(&Vt[bufi][mloc * LDSV + sp * 24]);
#pragma unroll
      for (int i = 0; i < 12; ++i) {
        dst[i] = f2bf(t[2 * i] * inv) | (f2bf(t[2 * i + 1] * inv) << 16);
      }
    }
    __syncthreads();

    // ---- GEMM: (128 x 96) @ (96 x 64) per tile; wave owns 32 c-rows
    float4v acc[2][4];
#pragma unroll
    for (int mf = 0; mf < 2; ++mf)
#pragma unroll
      for (int nf = 0; nf < 4; ++nf)
        acc[mf][nf] = (float4v){0.f, 0.f, 0.f, 0.f};

#pragma unroll
    for (int ks = 0; ks < 3; ++ks) {
      short8v bfr[4];
#pragma unroll
      for (int nf = 0; nf < 4; ++nf) {
        bfr[nf] = *(const short8v*)(&Vt[bufi][(nf * 16 + row16) * LDSV + ks * 32 + kgrp * 8]);
      }
#pragma unroll
      for (int mf = 0; mf < 2; ++mf)
#pragma unroll
        for (int nf = 0; nf < 4; ++nf)
          acc[mf][nf] = __builtin_amdgcn_mfma_f32_16x16x32_bf16(
              afr[mf][ks], bfr[nf], acc[mf][nf], 0, 0, 0);
    }

    // ---- permuted store: out[o][c][50-kw][kh]; C/D: col=lane&15 (m), row=kgrp*4+reg (c)
#pragma unroll
    for (int nf = 0; nf < 4; ++nf) {
      int m = m0 + nf * 16 + row16;
      if (m < NSP) {
        int kw = m / KHW;
        int kh = m - kw * KHW;
        float* ob = out + (size_t)o * (C_DIM * NSP) + (KHW - 1 - kw) * KHW + kh
                        + (size_t)(chalf * CB + wave * 32 + kgrp * 4) * NSP;
#pragma unroll
        for (int mf = 0; mf < 2; ++mf) {
#pragma unroll
          for (int r = 0; r < 4; ++r) {
            ob[(size_t)(mf * 16 + r) * NSP] = acc[mf][nf][r];
          }
        }
      }
    }
  }
}

extern "C" void kernel_launch(void* const* d_in, const int* in_sizes, int n_in,
                              void* d_out, int out_size, void* d_ws, size_t ws_size,
                              hipStream_t stream) {
  const float* xg  = (const float*)d_in[0];
  const float* wcp = (const float*)d_in[1];
  const float* rad = (const float*)d_in[2];
  const float* wts = (const float*)d_in[3];
  float* out = (float*)d_out;
  hipLaunchKernelGGL(smp_fused, dim3(O_DIM * CSPLIT * GROUPS), dim3(256), 0, stream,
                     xg, wcp, rad, wts, out);
}

// Round 3
// 303.056 us; speedup vs baseline: 1.3737x; 1.2349x over previous
//
#include <hip/hip_runtime.h>

#define O_DIM 256
#define C_DIM 256
#define P_DIM 96
#define KHW 51
#define NSP 2601      // 51*51
#define NT 64         // output-linear spatial tile
#define NTILES 41     // ceil(2601/64)
#define GROUPS 8      // contiguous tile-span groups per (o, c-quarter)
#define CSPLIT 4      // c dimension split across blocks
#define CB 64         // c rows per block (C_DIM / CSPLIT)
#define LDSV 104      // LDS row stride (bf16 elems)

typedef __attribute__((ext_vector_type(8))) short short8v;
typedef __attribute__((ext_vector_type(4))) float float4v;

__device__ __forceinline__ unsigned f2bf(float f) {
  union { float f; unsigned u; } v; v.f = f;
  return (v.u + 0x7FFFu + ((v.u >> 16) & 1u)) >> 16;  // RNE f32->bf16
}

__global__ __launch_bounds__(256) void smp_fused(
    const float* __restrict__ xg,   // (1,2,51,51)
    const float* __restrict__ wc,   // (O,P,2)
    const float* __restrict__ rad,  // (O,P,1,1)
    const float* __restrict__ wts,  // (O,C,P)
    float* __restrict__ out)        // (O,C,51,51) f32
{
  __shared__ unsigned short Vt[2][NT * LDSV];  // B^T tiles, double-buffered

  const int b = blockIdx.x;
  const int o = b >> 5;                 // / (CSPLIT*GROUPS)
  const int cq = (b >> 3) & 3;          // c-quarter
  const int grp = b & 7;
  const int tid = threadIdx.x;
  const int wave = tid >> 6;
  const int lane = tid & 63;
  const int row16 = lane & 15;
  const int kgrp = lane >> 4;

  // ---- A fragments: this block's 64 c-rows, wave owns 16 of them.
  // A[row=c][k=p]: lane holds row=(lane&15), k=kgrp*8+j, per 16x16x32 layout.
  short8v afr[3];  // [kstep]
  {
    const float* src = wts + ((size_t)o * C_DIM + cq * CB + wave * 16 + row16) * P_DIM;
#pragma unroll
    for (int ks = 0; ks < 3; ++ks) {
      const float4 a = *(const float4*)(src + ks * 32 + kgrp * 8);
      const float4 c = *(const float4*)(src + ks * 32 + kgrp * 8 + 4);
      short8v f;
      f[0] = (short)f2bf(a.x); f[1] = (short)f2bf(a.y);
      f[2] = (short)f2bf(a.z); f[3] = (short)f2bf(a.w);
      f[4] = (short)f2bf(c.x); f[5] = (short)f2bf(c.y);
      f[6] = (short)f2bf(c.z); f[7] = (short)f2bf(c.w);
      afr[ks] = f;
    }
  }

  // vals phase mapping: 4 threads per output location, each handles 24 of 96 points
  const int mloc = tid >> 2;  // 0..63 (offset within tile, output-linear)
  const int sp = tid & 3;     // 24-point chunk
  const float* wcp = wc + ((size_t)o * P_DIM + sp * 24) * 2;
  const float* rp  = rad + (size_t)o * P_DIM + sp * 24;

  const int t0 = (grp * NTILES) / GROUPS;
  const int t1 = ((grp + 1) * NTILES) / GROUPS;

  int bufi = 0;
  for (int tile = t0; tile < t1; ++tile, bufi ^= 1) {
    const int m0 = tile * NT;

    // ---- vals: triangular basis + count-normalize (exact IEEE chain for count)
    {
      int jl = m0 + mloc;                 // output-linear index
      int jc = jl < NSP ? jl : NSP - 1;
      int i = jc / KHW;                   // output row
      int jj = jc - i * KHW;              // output col
      int n = jj * KHW + (KHW - 1 - i);   // source spatial index
      float gy = xg[n];                   // ys component
      float gx = xg[NSP + n];             // xs component
      float t[24];
      int cnt = 0;
#pragma unroll
      for (int k = 0; k < 24; ++k) {
        float d = fabsf(wcp[2 * k] - gy) + fabsf(wcp[2 * k + 1] - gx);
        float v = 1.0f - d / rp[k];
        v = v > 0.0f ? v : 0.0f;
        t[k] = v;
        cnt += (v != 0.0f);
      }
      cnt += __shfl_xor(cnt, 1);
      cnt += __shfl_xor(cnt, 2);
      const float inv = 1.0f / ((float)cnt + 1e-6f);  // feeds bf16; 2-rounding ok
      unsigned* dst = (unsigned*)(&Vt[bufi][mloc * LDSV + sp * 24]);
#pragma unroll
      for (int k = 0; k < 12; ++k) {
        dst[k] = f2bf(t[2 * k] * inv) | (f2bf(t[2 * k + 1] * inv) << 16);
      }
    }
    __syncthreads();

    // ---- GEMM: (64 x 96) @ (96 x 64) per tile; wave owns 16 c-rows
    float4v acc[4];
#pragma unroll
    for (int nf = 0; nf < 4; ++nf)
      acc[nf] = (float4v){0.f, 0.f, 0.f, 0.f};

#pragma unroll
    for (int ks = 0; ks < 3; ++ks) {
      short8v bfr[4];
#pragma unroll
      for (int nf = 0; nf < 4; ++nf) {
        bfr[nf] = *(const short8v*)(&Vt[bufi][(nf * 16 + row16) * LDSV + ks * 32 + kgrp * 8]);
      }
#pragma unroll
      for (int nf = 0; nf < 4; ++nf)
        acc[nf] = __builtin_amdgcn_mfma_f32_16x16x32_bf16(
            afr[ks], bfr[nf], acc[nf], 0, 0, 0);
    }

    // ---- store: out[o][c][jl] with jl ascending & contiguous.
    // C/D layout: col(=jl offset)=lane&15, row(=c offset)=kgrp*4+reg
    {
      float* ob = out + (size_t)o * (C_DIM * NSP)
                      + (size_t)(cq * CB + wave * 16 + kgrp * 4) * NSP + m0 + row16;
#pragma unroll
      for (int nf = 0; nf < 4; ++nf) {
        int jl = m0 + nf * 16 + row16;
        if (jl < NSP) {
#pragma unroll
          for (int r = 0; r < 4; ++r) {
            ob[(size_t)r * NSP + nf * 16] = acc[nf][r];
          }
        }
      }
    }
  }
}

extern "C" void kernel_launch(void* const* d_in, const int* in_sizes, int n_in,
                              void* d_out, int out_size, void* d_ws, size_t ws_size,
                              hipStream_t stream) {
  const float* xg  = (const float*)d_in[0];
  const float* wcp = (const float*)d_in[1];
  const float* rad = (const float*)d_in[2];
  const float* wts = (const float*)d_in[3];
  float* out = (float*)d_out;
  hipLaunchKernelGGL(smp_fused, dim3(O_DIM * CSPLIT * GROUPS), dim3(256), 0, stream,
                     xg, wcp, rad, wts, out);
}